// Round 24
// baseline (285.286 us; speedup 1.0000x reference)
//
#include <hip/hip_runtime.h>
#include <cstdint>
#include <cstddef>

#define NN 50000
#define NE 800000
#define HID 256
#define TDIM 128

#define CHB 16384          // bins per histogram chunk (64 KB LDS)
#define NSL 64             // edge slices (256 fill blocks -> 1/CU)
#define SLE (NE / NSL)     // 12500 edges per slice

typedef short bf16x8 __attribute__((ext_vector_type(8)));
typedef float f32x4 __attribute__((ext_vector_type(4)));

#define GLOAD_LDS16(g, l)                                                        \
  __builtin_amdgcn_global_load_lds(                                              \
      (const __attribute__((address_space(1))) unsigned int*)(g),                \
      (__attribute__((address_space(3))) unsigned int*)(l), 16, 0, 0)

__device__ inline unsigned short f2bf(float f) {
  uint32_t u = __builtin_bit_cast(uint32_t, f);
  uint32_t r = u + 0x7FFFu + ((u >> 16) & 1u);
  return (unsigned short)(r >> 16);
}
__device__ inline float bf2f(unsigned short s) {
  uint32_t u = ((uint32_t)s) << 16;
  return __builtin_bit_cast(float, u);
}
__device__ inline float fast_sig(float x) {
  return __builtin_amdgcn_rcpf(1.0f + __expf(-x));
}
__device__ inline float fast_tanh(float x) {
  float xc = fminf(fmaxf(x, -10.0f), 10.0f);
  float e = __expf(2.0f * xc);
  return 1.0f - 2.0f * __builtin_amdgcn_rcpf(e + 1.0f);
}

// ---------------- prep A: hist_part (blocks 0..511) + cvt_hidden (blocks 512..) ----------------
__global__ __launch_bounds__(1024) void prep_a(const int* __restrict__ src,
                                               const int* __restrict__ dst,
                                               int* __restrict__ P,
                                               const float* __restrict__ x,
                                               short* __restrict__ xb,
                                               unsigned char* __restrict__ xf8) {
  const int b = blockIdx.x;
  if (b < 8 * NSL) {
    __shared__ int h[CHB];
    const int c = b & 7, s = b >> 3;
    for (int j = threadIdx.x; j < CHB; j += 1024) h[j] = 0;
    __syncthreads();
    const int* arr = (c < 4) ? src : dst;
    const int base = (c & 3) * CHB;
    const int e0 = s * SLE;
    for (int i = threadIdx.x; i < SLE; i += 1024) {
      int v = arr[e0 + i] - base;
      if ((unsigned)v < CHB) atomicAdd(&h[v], 1);
    }
    __syncthreads();
    int* Pc = P + (size_t)(c * NSL + s) * CHB;
    for (int j = threadIdx.x; j < CHB; j += 1024) Pc[j] = h[j];
  } else {
    int i = (b - 8 * NSL) * 1024 + threadIdx.x;
    if (i < NN * HID / 4) {
      float4 v = ((const float4*)x)[i];
      unsigned int lo = (unsigned int)f2bf(v.x) | ((unsigned int)f2bf(v.y) << 16);
      unsigned int hi = (unsigned int)f2bf(v.z) | ((unsigned int)f2bf(v.w) << 16);
      ((uint2*)xb)[i] = make_uint2(lo, hi);
      unsigned int f8 = __builtin_amdgcn_cvt_pk_fp8_f32(v.x, v.y, 0u, false);
      f8 = __builtin_amdgcn_cvt_pk_fp8_f32(v.z, v.w, f8, true);
      ((unsigned int*)xf8)[i] = f8;
    }
  }
}

// ---------------- phase B: reduce -> norms; in-place slice scan ----------------
__global__ __launch_bounds__(256) void hist_reduce(int* __restrict__ P,
                                                   float* __restrict__ onorm,
                                                   float* __restrict__ inorm,
                                                   int* __restrict__ icnt) {
  int n = blockIdx.x * 256 + threadIdx.x;
  if (n >= 4 * CHB) return;
  const int c = n >> 14, j = n & (CHB - 1);
  int* Po = P + (size_t)(c * NSL) * CHB + j;
  int od = 0;
#pragma unroll 8
  for (int s = 0; s < NSL; ++s) od += Po[(size_t)s * CHB];
  int* Pi = P + (size_t)((4 + c) * NSL) * CHB + j;
  int run = 0;
#pragma unroll 8
  for (int s = 0; s < NSL; ++s) { int t = Pi[(size_t)s * CHB]; Pi[(size_t)s * CHB] = run; run += t; }
  if (n < NN) {
    onorm[n] = 1.0f / sqrtf(fmaxf((float)od, 1.0f));
    inorm[n] = 1.0f / sqrtf(fmaxf((float)run, 1.0f));
    icnt[n] = run;
  }
}

// ---------------- CSR row scan ----------------
__global__ __launch_bounds__(1024) void scan_rows(const int* __restrict__ icnt,
                                                  int* __restrict__ rowstart) {
  __shared__ int wsum[16];
  __shared__ int carry_s;
  const int tid = threadIdx.x, lane = tid & 63, w = tid >> 6;
  if (tid == 0) { carry_s = 0; rowstart[0] = 0; }
  __syncthreads();
  for (int base = 0; base < NN; base += 8192) {
    int i0 = base + tid * 8;
    int c[8];
    int v = 0;
#pragma unroll
    for (int j = 0; j < 8; ++j) {
      int i = i0 + j;
      c[j] = (i < NN) ? icnt[i] : 0;
      v += c[j];
    }
    int inc = v;
#pragma unroll
    for (int off = 1; off < 64; off <<= 1) {
      int t = __shfl_up(inc, off, 64);
      if (lane >= off) inc += t;
    }
    if (lane == 63) wsum[w] = inc;
    __syncthreads();
    int woff = 0;
    for (int k = 0; k < w; ++k) woff += wsum[k];
    int carry = carry_s;
    int run = carry + woff + inc - v;
#pragma unroll
    for (int j = 0; j < 8; ++j) {
      int i = i0 + j;
      if (i < NN) rowstart[i + 1] = run + c[j];
      run += c[j];
    }
    __syncthreads();
    if (tid == 1023) carry_s = carry + woff + inc;
    __syncthreads();
  }
}

// ---------------- CSR fill via LDS cursors; packed (src, weight) 8B records ----------------
__global__ __launch_bounds__(1024) void fill_csr2(const int* __restrict__ src,
                                                  const int* __restrict__ dst,
                                                  const float* __restrict__ onorm,
                                                  const int* __restrict__ rowstart,
                                                  const int* __restrict__ P,
                                                  uint2* __restrict__ epk) {
  __shared__ int cur[CHB];
  const int b = blockIdx.x;          // 4 * NSL blocks
  const int c = b & 3, s = b >> 2;
  const int base = c * CHB;
  const int* Pi = P + (size_t)((4 + c) * NSL + s) * CHB;
  for (int j = threadIdx.x; j < CHB; j += 1024) {
    int n = base + j;
    cur[j] = (n < NN ? rowstart[n] : 0) + Pi[j];
  }
  __syncthreads();
  const int e0 = s * SLE;
  for (int i = threadIdx.x; i < SLE; i += 1024) {
    int d = dst[e0 + i] - base;
    if ((unsigned)d < CHB) {
      int sv = src[e0 + i];
      int pos = atomicAdd(&cur[d], 1);
      epk[pos] = make_uint2((unsigned)sv, __builtin_bit_cast(unsigned, onorm[sv]));
    }
  }
}

// ---------------- gather aggregation v4: fp8 rows, packed edge records ----------------
__global__ __launch_bounds__(256) void gather_agg(const unsigned char* __restrict__ xF8,
                                                  const int* __restrict__ rowstart,
                                                  const uint2* __restrict__ epk,
                                                  const float* __restrict__ inorm,
                                                  short* __restrict__ aggB) {
  const int wid = blockIdx.x * 4 + (threadIdx.x >> 6);
  const int l = threadIdx.x & 63;
  if (wid >= NN) return;
  const int half = l >> 5;
  const int fo2 = (l & 31) * 8;
  const int e1 = rowstart[wid + 1];
  int e = rowstart[wid];
  float a[8] = {0.f, 0.f, 0.f, 0.f, 0.f, 0.f, 0.f, 0.f};

  for (; e + 8 <= e1; e += 8) {
    uint2 pe[4]; uint2 uu[4];
#pragma unroll
    for (int q = 0; q < 4; ++q) pe[q] = epk[e + q * 2 + half];
#pragma unroll
    for (int q = 0; q < 4; ++q) uu[q] = *(const uint2*)(xF8 + (size_t)pe[q].x * HID + fo2);
#pragma unroll
    for (int q = 0; q < 4; ++q) {
      float wq = __builtin_bit_cast(float, pe[q].y);
      a[0] = fmaf(__builtin_amdgcn_cvt_f32_fp8(uu[q].x, 0), wq, a[0]);
      a[1] = fmaf(__builtin_amdgcn_cvt_f32_fp8(uu[q].x, 1), wq, a[1]);
      a[2] = fmaf(__builtin_amdgcn_cvt_f32_fp8(uu[q].x, 2), wq, a[2]);
      a[3] = fmaf(__builtin_amdgcn_cvt_f32_fp8(uu[q].x, 3), wq, a[3]);
      a[4] = fmaf(__builtin_amdgcn_cvt_f32_fp8(uu[q].y, 0), wq, a[4]);
      a[5] = fmaf(__builtin_amdgcn_cvt_f32_fp8(uu[q].y, 1), wq, a[5]);
      a[6] = fmaf(__builtin_amdgcn_cvt_f32_fp8(uu[q].y, 2), wq, a[6]);
      a[7] = fmaf(__builtin_amdgcn_cvt_f32_fp8(uu[q].y, 3), wq, a[7]);
    }
  }
  for (; e < e1; e += 2) {
    int idx = e + half;
    bool v = idx < e1;
    uint2 pe = v ? epk[idx] : make_uint2(0u, 0u);
    float w0 = v ? __builtin_bit_cast(float, pe.y) : 0.0f;
    uint2 u = *(const uint2*)(xF8 + (size_t)pe.x * HID + fo2);
    a[0] = fmaf(__builtin_amdgcn_cvt_f32_fp8(u.x, 0), w0, a[0]);
    a[1] = fmaf(__builtin_amdgcn_cvt_f32_fp8(u.x, 1), w0, a[1]);
    a[2] = fmaf(__builtin_amdgcn_cvt_f32_fp8(u.x, 2), w0, a[2]);
    a[3] = fmaf(__builtin_amdgcn_cvt_f32_fp8(u.x, 3), w0, a[3]);
    a[4] = fmaf(__builtin_amdgcn_cvt_f32_fp8(u.y, 0), w0, a[4]);
    a[5] = fmaf(__builtin_amdgcn_cvt_f32_fp8(u.y, 1), w0, a[5]);
    a[6] = fmaf(__builtin_amdgcn_cvt_f32_fp8(u.y, 2), w0, a[6]);
    a[7] = fmaf(__builtin_amdgcn_cvt_f32_fp8(u.y, 3), w0, a[7]);
  }

#pragma unroll
  for (int k = 0; k < 8; ++k) a[k] += __shfl_xor(a[k], 32);

  if (l < 32) {
    const float wi = inorm[wid];
    uint4 o;
    o.x = (unsigned int)f2bf(a[0] * wi) | ((unsigned int)f2bf(a[1] * wi) << 16);
    o.y = (unsigned int)f2bf(a[2] * wi) | ((unsigned int)f2bf(a[3] * wi) << 16);
    o.z = (unsigned int)f2bf(a[4] * wi) | ((unsigned int)f2bf(a[5] * wi) << 16);
    o.w = (unsigned int)f2bf(a[6] * wi) | ((unsigned int)f2bf(a[7] * wi) << 16);
    *(uint4*)(aggB + (size_t)wid * HID + fo2) = o;
  }
}

// ---------------- fused weight prep ----------------
__global__ __launch_bounds__(256) void wprep(const float* __restrict__ W1,
                                             const float* __restrict__ W2,
                                             const float* __restrict__ W_ih,
                                             const float* __restrict__ W_hh,
                                             const float* __restrict__ t,
                                             const float* __restrict__ tw,
                                             const float* __restrict__ tb,
                                             const float* __restrict__ b_ih,
                                             const float* __restrict__ b_hh,
                                             short* __restrict__ W1B,
                                             short* __restrict__ W2B,
                                             short* __restrict__ WgB,
                                             float* __restrict__ cst) {
  const int b = blockIdx.x;
  const int k = threadIdx.x;
  if (b < 256) {
    W1B[b * 256 + k] = (short)f2bf(W1[k * 256 + b]);
    W2B[b * 256 + k] = (short)f2bf(W2[k * 256 + b]);
  } else if (b < 512) {
    int u = b - 256;
    int base = (u >> 4) * 64 + (u & 15);
    float v0 = W_ih[(size_t)u * 384 + k] + W_hh[(size_t)u * 256 + k];
    float v1 = W_ih[(size_t)(256 + u) * 384 + k] + W_hh[(size_t)(256 + u) * 256 + k];
    float v2 = W_ih[(size_t)(512 + u) * 384 + k];
    float v3 = W_hh[(size_t)(512 + u) * 256 + k];
    WgB[(size_t)(base + 0)  * 256 + k] = (short)f2bf(v0);
    WgB[(size_t)(base + 16) * 256 + k] = (short)f2bf(v1);
    WgB[(size_t)(base + 32) * 256 + k] = (short)f2bf(v2);
    WgB[(size_t)(base + 48) * 256 + k] = (short)f2bf(v3);
  } else {
    __shared__ float te[TDIM];
    int u = k;
    if (u < TDIM) te[u] = cosf(t[0] * tw[u] + tb[u]);
    __syncthreads();
    float cr = b_ih[u] + b_hh[u];
    float cz = b_ih[256 + u] + b_hh[256 + u];
    float ci = b_ih[512 + u];
    for (int kk = 0; kk < TDIM; ++kk) {
      float tk = te[kk];
      cr = fmaf(tk, W_ih[(size_t)u * 384 + 256 + kk], cr);
      cz = fmaf(tk, W_ih[(size_t)(256 + u) * 384 + 256 + kk], cz);
      ci = fmaf(tk, W_ih[(size_t)(512 + u) * 384 + 256 + kk], ci);
    }
    cst[u] = cr;
    cst[256 + u] = cz;
    cst[512 + u] = ci;
    cst[768 + u] = b_hh[512 + u];
  }
}

// ---------------- panel GEMM v3: 8 waves = 4 row-groups x 2 panel-parities ----------------
// 64-row blocks (782), 512 threads. Wave w: rows (w&3)*16.., panels p = 2r + (w>>2).
// Pair round r stages panels {2r, 2r+1} into Ps[0..1] (64 KB, all 8 waves cooperate);
// each wave computes only its parity -> per-wave chain halves; 2 blocks/CU = 16 waves.
// Fragment math, XOR swizzle, epilogues byte-identical to the R23-verified kernel.
template <int NP, bool GRUE, bool BF16O, bool F8O>
__global__ __launch_bounds__(512, 4) void panel_gemm(const short* __restrict__ A,
                                                     const short* __restrict__ WB,
                                                     const float* __restrict__ bias,
                                                     const float* __restrict__ cst,
                                                     short* __restrict__ outH,
                                                     unsigned char* __restrict__ outF8,
                                                     float* __restrict__ outF) {
  __shared__ __align__(16) short Ps[2][64 * 256];   // 2 x 32 KB

  const int row0 = blockIdx.x * 64;
  const int tid = threadIdx.x;
  const int l = tid & 63, wv = tid >> 6;
  const int rowgrp = wv & 3, parity = wv >> 2;
  const int fr = l & 15, fg = l >> 4;

  // stage panel pair 0 ({0,1}) -- 4096 chunks, 8 per thread; wave-uniform base holds
#pragma unroll
  for (int i = 0; i < 8; ++i) {
    int id = tid + i * 512;             // 0..4095
    int pp = id >> 11;                  // which panel of the pair
    int cid = id & 2047;
    int row = cid >> 5, kc = cid & 31;
    GLOAD_LDS16(WB + (size_t)(pp * 64 + row) * HID + ((kc ^ (row & 15)) << 3),
                Ps[pp] + cid * 8);
  }

  // A-frags -> registers ONCE (16 rows per row-group)
  int ar = row0 + rowgrp * 16 + fr;
  ar = ar < NN ? ar : NN - 1;
  bf16x8 af[8];
#pragma unroll
  for (int t = 0; t < 8; ++t)
    af[t] = *(const bf16x8*)(A + (size_t)ar * HID + t * 32 + fg * 8);

  __syncthreads();   // pair 0 + A-frags landed

#pragma unroll
  for (int r = 0; r < NP / 2; ++r) {
    const int p = 2 * r + parity;
    f32x4 acc[4];
    acc[0] = acc[1] = acc[2] = acc[3] = (f32x4)(0.0f);
#pragma unroll
    for (int t = 0; t < 8; ++t) {
#pragma unroll
      for (int nf = 0; nf < 4; ++nf) {
        int rr = nf * 16 + fr;
        bf16x8 bh = *(const bf16x8*)(Ps[parity] + rr * 256 + (((t * 4 + fg) ^ (rr & 15)) << 3));
        acc[nf] = __builtin_amdgcn_mfma_f32_16x16x32_bf16(af[t], bh, acc[nf], 0, 0, 0);
      }
    }

    if constexpr (!GRUE) {
#pragma unroll
      for (int nf = 0; nf < 4; ++nf) {
        int c = p * 64 + nf * 16 + fr;
        float bs = bias[c];
#pragma unroll
        for (int j = 0; j < 4; ++j) {
          int row = row0 + rowgrp * 16 + fg * 4 + j;
          if (row < NN) {
            float v = fmaxf(acc[nf][j] + bs, 0.0f);
            size_t off = (size_t)row * HID + c;
            if constexpr (BF16O) outH[off] = (short)f2bf(v);
            if constexpr (F8O) {
              unsigned int r8 = __builtin_amdgcn_cvt_pk_fp8_f32(v, v, 0u, false);
              outF8[off] = (unsigned char)(r8 & 0xFF);
            }
          }
        }
      }
    } else {
      const int u = p * 16 + fr;
      const float cr = cst[u], cz = cst[256 + u], ci = cst[512 + u], chn = cst[768 + u];
#pragma unroll
      for (int j = 0; j < 4; ++j) {
        int row = row0 + rowgrp * 16 + fg * 4 + j;
        if (row < NN) {
          float dr = acc[0][j] + cr;
          float dz = acc[1][j] + cz;
          float dn = acc[2][j] + ci;
          float dh = acc[3][j] + chn;
          float rg = fast_sig(dr);
          float zg = fast_sig(dz);
          float ng = fast_tanh(dn + rg * dh);
          size_t off = (size_t)row * HID + u;
          float hv = bf2f((unsigned short)A[off]);
          outF[off] = (1.0f - zg) * ng + zg * hv;
        }
      }
    }

    if (r + 1 < NP / 2) {
      __syncthreads();   // all waves done reading Ps
#pragma unroll
      for (int i = 0; i < 8; ++i) {
        int id = tid + i * 512;
        int pp = id >> 11;
        int cid = id & 2047;
        int row = cid >> 5, kc = cid & 31;
        GLOAD_LDS16(WB + (size_t)((2 * (r + 1) + pp) * 64 + row) * HID + ((kc ^ (row & 15)) << 3),
                    Ps[pp] + cid * 8);
      }
      __syncthreads();   // next pair landed (implicit vmcnt drain)
    }
  }
}

extern "C" void kernel_launch(void* const* d_in, const int* in_sizes, int n_in,
                              void* d_out, int out_size, void* d_ws, size_t ws_size,
                              hipStream_t stream) {
  const float* hidden = (const float*)d_in[0];
  const float* t      = (const float*)d_in[1];
  const int*   src    = (const int*)d_in[2];
  const int*   dst    = (const int*)d_in[3];
  const float* W1     = (const float*)d_in[4];
  const float* b1     = (const float*)d_in[5];
  const float* W2     = (const float*)d_in[6];
  const float* b2     = (const float*)d_in[7];
  const float* time_w = (const float*)d_in[8];
  const float* time_b = (const float*)d_in[9];
  const float* W_ih   = (const float*)d_in[10];
  const float* W_hh   = (const float*)d_in[11];
  const float* b_ih   = (const float*)d_in[12];
  const float* b_hh   = (const float*)d_in[13];
  float* out = (float*)d_out;

  char* p = (char*)d_ws;
  float* onorm = (float*)p;      p += 50048 * 4;
  float* inorm = (float*)p;      p += 50048 * 4;
  float* cst   = (float*)p;      p += 1024 * 4;
  int* rowstart = (int*)p;       p += 50052 * 4;
  int* icnt     = (int*)p;       p += 50048 * 4;
  uint2* epk    = (uint2*)p;     p += 800000 * 8;
  const size_t NFE = (size_t)NN * HID;
  short* Xb   = (short*)p;       p += NFE * 2;
  short* aggB = (short*)p;       p += NFE * 2;
  short* h1B  = (short*)p;       p += NFE * 2;   // P scratch only (dead plane)
  short* h2B  = (short*)p;       p += NFE * 2;
  unsigned char* Xf8  = (unsigned char*)p;  p += NFE;
  unsigned char* h1F8 = (unsigned char*)p;  p += NFE;
  short* W1B  = (short*)p;       p += 65536 * 2;
  short* W2B  = (short*)p;       p += 65536 * 2;
  short* WgB  = (short*)p;       p += 262144 * 2;
  // P = 8*NSL*CHB ints = 33.5 MB over h1B+h2B (51.2 MB contiguous); consumed by
  // fill_csr2 before the layer-2 GEMM writes h2B (stream-ordered).
  int* P = (int*)h1B;

  // prep A: histograms + hidden->bf16/fp8 in one launch; weight prep
  const int cvt_blocks = (NN * HID / 4 + 1023) / 1024;
  prep_a<<<8 * NSL + cvt_blocks, 1024, 0, stream>>>(src, dst, P, hidden, Xb, Xf8);
  wprep<<<513, 256, 0, stream>>>(W1, W2, W_ih, W_hh, t, time_w, time_b, b_ih, b_hh,
                                 W1B, W2B, WgB, cst);

  // graph prep: norms/prefix -> row scan -> LDS-cursor fill (packed records)
  hist_reduce<<<(4 * CHB + 255) / 256, 256, 0, stream>>>(P, onorm, inorm, icnt);
  scan_rows<<<1, 1024, 0, stream>>>(icnt, rowstart);
  fill_csr2<<<4 * NSL, 1024, 0, stream>>>(src, dst, onorm, rowstart, P, epk);

  const int gather_blocks = (NN + 3) / 4;
  const int gblocks = (NN + 63) / 64;   // 782

  // layer 1: fp8 gather + A-resident panel GEMM -> fp8 h1 plane only
  gather_agg<<<gather_blocks, 256, 0, stream>>>(Xf8, rowstart, epk, inorm, aggB);
  panel_gemm<4, false, false, true><<<gblocks, 512, 0, stream>>>(aggB, W1B, b1, nullptr, nullptr, h1F8, nullptr);

  // layer 2: fp8 gather + panel GEMM -> bf16 h2
  gather_agg<<<gather_blocks, 256, 0, stream>>>(h1F8, rowstart, epk, inorm, aggB);
  panel_gemm<4, false, true, false><<<gblocks, 512, 0, stream>>>(aggB, W2B, b2, nullptr, h2B, nullptr, nullptr);

  // GRU: 16 gate panels over 1024 Wg cols (8 pair rounds), fused gate epilogue -> out
  panel_gemm<16, true, false, false><<<gblocks, 512, 0, stream>>>(h2B, WgB, nullptr, cst, nullptr, nullptr, out);
}

// Round 25
// 268.219 us; speedup vs baseline: 1.0636x; 1.0636x over previous
//
#include <hip/hip_runtime.h>
#include <cstdint>
#include <cstddef>

#define NN 50000
#define NE 800000
#define HID 256
#define TDIM 128

#define CHB 16384          // bins per histogram chunk (64 KB LDS)
#define NSL 64             // edge slices (256 fill blocks -> 1/CU)
#define SLE (NE / NSL)     // 12500 edges per slice

typedef short bf16x8 __attribute__((ext_vector_type(8)));
typedef float f32x4 __attribute__((ext_vector_type(4)));

#define GLOAD_LDS16(g, l)                                                        \
  __builtin_amdgcn_global_load_lds(                                              \
      (const __attribute__((address_space(1))) unsigned int*)(g),                \
      (__attribute__((address_space(3))) unsigned int*)(l), 16, 0, 0)

__device__ inline unsigned short f2bf(float f) {
  uint32_t u = __builtin_bit_cast(uint32_t, f);
  uint32_t r = u + 0x7FFFu + ((u >> 16) & 1u);
  return (unsigned short)(r >> 16);
}
__device__ inline float bf2f(unsigned short s) {
  uint32_t u = ((uint32_t)s) << 16;
  return __builtin_bit_cast(float, u);
}
__device__ inline float fast_sig(float x) {
  return __builtin_amdgcn_rcpf(1.0f + __expf(-x));
}
__device__ inline float fast_tanh(float x) {
  float xc = fminf(fmaxf(x, -10.0f), 10.0f);
  float e = __expf(2.0f * xc);
  return 1.0f - 2.0f * __builtin_amdgcn_rcpf(e + 1.0f);
}

// ---------------- prep A: hist_part (blocks 0..511) + cvt_hidden (blocks 512..) ----------------
__global__ __launch_bounds__(1024) void prep_a(const int* __restrict__ src,
                                               const int* __restrict__ dst,
                                               int* __restrict__ P,
                                               const float* __restrict__ x,
                                               short* __restrict__ xb,
                                               unsigned char* __restrict__ xf8) {
  const int b = blockIdx.x;
  if (b < 8 * NSL) {
    __shared__ int h[CHB];
    const int c = b & 7, s = b >> 3;
    for (int j = threadIdx.x; j < CHB; j += 1024) h[j] = 0;
    __syncthreads();
    const int* arr = (c < 4) ? src : dst;
    const int base = (c & 3) * CHB;
    const int e0 = s * SLE;
    for (int i = threadIdx.x; i < SLE; i += 1024) {
      int v = arr[e0 + i] - base;
      if ((unsigned)v < CHB) atomicAdd(&h[v], 1);
    }
    __syncthreads();
    int* Pc = P + (size_t)(c * NSL + s) * CHB;
    for (int j = threadIdx.x; j < CHB; j += 1024) Pc[j] = h[j];
  } else {
    int i = (b - 8 * NSL) * 1024 + threadIdx.x;
    if (i < NN * HID / 4) {
      float4 v = ((const float4*)x)[i];
      unsigned int lo = (unsigned int)f2bf(v.x) | ((unsigned int)f2bf(v.y) << 16);
      unsigned int hi = (unsigned int)f2bf(v.z) | ((unsigned int)f2bf(v.w) << 16);
      ((uint2*)xb)[i] = make_uint2(lo, hi);
      unsigned int f8 = __builtin_amdgcn_cvt_pk_fp8_f32(v.x, v.y, 0u, false);
      f8 = __builtin_amdgcn_cvt_pk_fp8_f32(v.z, v.w, f8, true);
      ((unsigned int*)xf8)[i] = f8;
    }
  }
}

// ---------------- phase B: reduce -> norms; in-place slice scan ----------------
__global__ __launch_bounds__(256) void hist_reduce(int* __restrict__ P,
                                                   float* __restrict__ onorm,
                                                   float* __restrict__ inorm,
                                                   int* __restrict__ icnt) {
  int n = blockIdx.x * 256 + threadIdx.x;
  if (n >= 4 * CHB) return;
  const int c = n >> 14, j = n & (CHB - 1);
  int* Po = P + (size_t)(c * NSL) * CHB + j;
  int od = 0;
#pragma unroll 8
  for (int s = 0; s < NSL; ++s) od += Po[(size_t)s * CHB];
  int* Pi = P + (size_t)((4 + c) * NSL) * CHB + j;
  int run = 0;
#pragma unroll 8
  for (int s = 0; s < NSL; ++s) { int t = Pi[(size_t)s * CHB]; Pi[(size_t)s * CHB] = run; run += t; }
  if (n < NN) {
    onorm[n] = 1.0f / sqrtf(fmaxf((float)od, 1.0f));
    inorm[n] = 1.0f / sqrtf(fmaxf((float)run, 1.0f));
    icnt[n] = run;
  }
}

// ---------------- CSR row scan ----------------
__global__ __launch_bounds__(1024) void scan_rows(const int* __restrict__ icnt,
                                                  int* __restrict__ rowstart) {
  __shared__ int wsum[16];
  __shared__ int carry_s;
  const int tid = threadIdx.x, lane = tid & 63, w = tid >> 6;
  if (tid == 0) { carry_s = 0; rowstart[0] = 0; }
  __syncthreads();
  for (int base = 0; base < NN; base += 8192) {
    int i0 = base + tid * 8;
    int c[8];
    int v = 0;
#pragma unroll
    for (int j = 0; j < 8; ++j) {
      int i = i0 + j;
      c[j] = (i < NN) ? icnt[i] : 0;
      v += c[j];
    }
    int inc = v;
#pragma unroll
    for (int off = 1; off < 64; off <<= 1) {
      int t = __shfl_up(inc, off, 64);
      if (lane >= off) inc += t;
    }
    if (lane == 63) wsum[w] = inc;
    __syncthreads();
    int woff = 0;
    for (int k = 0; k < w; ++k) woff += wsum[k];
    int carry = carry_s;
    int run = carry + woff + inc - v;
#pragma unroll
    for (int j = 0; j < 8; ++j) {
      int i = i0 + j;
      if (i < NN) rowstart[i + 1] = run + c[j];
      run += c[j];
    }
    __syncthreads();
    if (tid == 1023) carry_s = carry + woff + inc;
    __syncthreads();
  }
}

// ---------------- CSR fill via LDS cursors; packed (src, weight) 8B records ----------------
__global__ __launch_bounds__(1024) void fill_csr2(const int* __restrict__ src,
                                                  const int* __restrict__ dst,
                                                  const float* __restrict__ onorm,
                                                  const int* __restrict__ rowstart,
                                                  const int* __restrict__ P,
                                                  uint2* __restrict__ epk) {
  __shared__ int cur[CHB];
  const int b = blockIdx.x;          // 4 * NSL blocks
  const int c = b & 3, s = b >> 2;
  const int base = c * CHB;
  const int* Pi = P + (size_t)((4 + c) * NSL + s) * CHB;
  for (int j = threadIdx.x; j < CHB; j += 1024) {
    int n = base + j;
    cur[j] = (n < NN ? rowstart[n] : 0) + Pi[j];
  }
  __syncthreads();
  const int e0 = s * SLE;
  for (int i = threadIdx.x; i < SLE; i += 1024) {
    int d = dst[e0 + i] - base;
    if ((unsigned)d < CHB) {
      int sv = src[e0 + i];
      int pos = atomicAdd(&cur[d], 1);
      epk[pos] = make_uint2((unsigned)sv, __builtin_bit_cast(unsigned, onorm[sv]));
    }
  }
}

// ---------------- gather aggregation v4: fp8 rows, packed edge records ----------------
__global__ __launch_bounds__(256) void gather_agg(const unsigned char* __restrict__ xF8,
                                                  const int* __restrict__ rowstart,
                                                  const uint2* __restrict__ epk,
                                                  const float* __restrict__ inorm,
                                                  short* __restrict__ aggB) {
  const int wid = blockIdx.x * 4 + (threadIdx.x >> 6);
  const int l = threadIdx.x & 63;
  if (wid >= NN) return;
  const int half = l >> 5;
  const int fo2 = (l & 31) * 8;
  const int e1 = rowstart[wid + 1];
  int e = rowstart[wid];
  float a[8] = {0.f, 0.f, 0.f, 0.f, 0.f, 0.f, 0.f, 0.f};

  for (; e + 8 <= e1; e += 8) {
    uint2 pe[4]; uint2 uu[4];
#pragma unroll
    for (int q = 0; q < 4; ++q) pe[q] = epk[e + q * 2 + half];
#pragma unroll
    for (int q = 0; q < 4; ++q) uu[q] = *(const uint2*)(xF8 + (size_t)pe[q].x * HID + fo2);
#pragma unroll
    for (int q = 0; q < 4; ++q) {
      float wq = __builtin_bit_cast(float, pe[q].y);
      a[0] = fmaf(__builtin_amdgcn_cvt_f32_fp8(uu[q].x, 0), wq, a[0]);
      a[1] = fmaf(__builtin_amdgcn_cvt_f32_fp8(uu[q].x, 1), wq, a[1]);
      a[2] = fmaf(__builtin_amdgcn_cvt_f32_fp8(uu[q].x, 2), wq, a[2]);
      a[3] = fmaf(__builtin_amdgcn_cvt_f32_fp8(uu[q].x, 3), wq, a[3]);
      a[4] = fmaf(__builtin_amdgcn_cvt_f32_fp8(uu[q].y, 0), wq, a[4]);
      a[5] = fmaf(__builtin_amdgcn_cvt_f32_fp8(uu[q].y, 1), wq, a[5]);
      a[6] = fmaf(__builtin_amdgcn_cvt_f32_fp8(uu[q].y, 2), wq, a[6]);
      a[7] = fmaf(__builtin_amdgcn_cvt_f32_fp8(uu[q].y, 3), wq, a[7]);
    }
  }
  for (; e < e1; e += 2) {
    int idx = e + half;
    bool v = idx < e1;
    uint2 pe = v ? epk[idx] : make_uint2(0u, 0u);
    float w0 = v ? __builtin_bit_cast(float, pe.y) : 0.0f;
    uint2 u = *(const uint2*)(xF8 + (size_t)pe.x * HID + fo2);
    a[0] = fmaf(__builtin_amdgcn_cvt_f32_fp8(u.x, 0), w0, a[0]);
    a[1] = fmaf(__builtin_amdgcn_cvt_f32_fp8(u.x, 1), w0, a[1]);
    a[2] = fmaf(__builtin_amdgcn_cvt_f32_fp8(u.x, 2), w0, a[2]);
    a[3] = fmaf(__builtin_amdgcn_cvt_f32_fp8(u.x, 3), w0, a[3]);
    a[4] = fmaf(__builtin_amdgcn_cvt_f32_fp8(u.y, 0), w0, a[4]);
    a[5] = fmaf(__builtin_amdgcn_cvt_f32_fp8(u.y, 1), w0, a[5]);
    a[6] = fmaf(__builtin_amdgcn_cvt_f32_fp8(u.y, 2), w0, a[6]);
    a[7] = fmaf(__builtin_amdgcn_cvt_f32_fp8(u.y, 3), w0, a[7]);
  }

#pragma unroll
  for (int k = 0; k < 8; ++k) a[k] += __shfl_xor(a[k], 32);

  if (l < 32) {
    const float wi = inorm[wid];
    uint4 o;
    o.x = (unsigned int)f2bf(a[0] * wi) | ((unsigned int)f2bf(a[1] * wi) << 16);
    o.y = (unsigned int)f2bf(a[2] * wi) | ((unsigned int)f2bf(a[3] * wi) << 16);
    o.z = (unsigned int)f2bf(a[4] * wi) | ((unsigned int)f2bf(a[5] * wi) << 16);
    o.w = (unsigned int)f2bf(a[6] * wi) | ((unsigned int)f2bf(a[7] * wi) << 16);
    *(uint4*)(aggB + (size_t)wid * HID + fo2) = o;
  }
}

// ---------------- fused weight prep ----------------
__global__ __launch_bounds__(256) void wprep(const float* __restrict__ W1,
                                             const float* __restrict__ W2,
                                             const float* __restrict__ W_ih,
                                             const float* __restrict__ W_hh,
                                             const float* __restrict__ t,
                                             const float* __restrict__ tw,
                                             const float* __restrict__ tb,
                                             const float* __restrict__ b_ih,
                                             const float* __restrict__ b_hh,
                                             short* __restrict__ W1B,
                                             short* __restrict__ W2B,
                                             short* __restrict__ WgB,
                                             float* __restrict__ cst) {
  const int b = blockIdx.x;
  const int k = threadIdx.x;
  if (b < 256) {
    W1B[b * 256 + k] = (short)f2bf(W1[k * 256 + b]);
    W2B[b * 256 + k] = (short)f2bf(W2[k * 256 + b]);
  } else if (b < 512) {
    int u = b - 256;
    int base = (u >> 4) * 64 + (u & 15);
    float v0 = W_ih[(size_t)u * 384 + k] + W_hh[(size_t)u * 256 + k];
    float v1 = W_ih[(size_t)(256 + u) * 384 + k] + W_hh[(size_t)(256 + u) * 256 + k];
    float v2 = W_ih[(size_t)(512 + u) * 384 + k];
    float v3 = W_hh[(size_t)(512 + u) * 256 + k];
    WgB[(size_t)(base + 0)  * 256 + k] = (short)f2bf(v0);
    WgB[(size_t)(base + 16) * 256 + k] = (short)f2bf(v1);
    WgB[(size_t)(base + 32) * 256 + k] = (short)f2bf(v2);
    WgB[(size_t)(base + 48) * 256 + k] = (short)f2bf(v3);
  } else {
    __shared__ float te[TDIM];
    int u = k;
    if (u < TDIM) te[u] = cosf(t[0] * tw[u] + tb[u]);
    __syncthreads();
    float cr = b_ih[u] + b_hh[u];
    float cz = b_ih[256 + u] + b_hh[256 + u];
    float ci = b_ih[512 + u];
    for (int kk = 0; kk < TDIM; ++kk) {
      float tk = te[kk];
      cr = fmaf(tk, W_ih[(size_t)u * 384 + 256 + kk], cr);
      cz = fmaf(tk, W_ih[(size_t)(256 + u) * 384 + 256 + kk], cz);
      ci = fmaf(tk, W_ih[(size_t)(512 + u) * 384 + 256 + kk], ci);
    }
    cst[u] = cr;
    cst[256 + u] = cz;
    cst[512 + u] = ci;
    cst[768 + u] = b_hh[512 + u];
  }
}

// ---------------- panel GEMM (R23-verified, occ 3) ----------------
// BF16O: write bf16 plane. F8O: write fp8 plane. GRUE: fused gate epilogue.
template <int NP, bool GRUE, bool BF16O, bool F8O>
__global__ __launch_bounds__(256, 3) void panel_gemm(const short* __restrict__ A,
                                                     const short* __restrict__ WB,
                                                     const float* __restrict__ bias,
                                                     const float* __restrict__ cst,
                                                     short* __restrict__ outH,
                                                     unsigned char* __restrict__ outF8,
                                                     float* __restrict__ outF) {
  __shared__ __align__(16) short Ps[64 * 256];   // 32 KB

  const int row0 = blockIdx.x * 64;
  const int tid = threadIdx.x;
  const int l = tid & 63, w = tid >> 6;
  const int fr = l & 15, fg = l >> 4;

  // stage panel 0 (linear LDS dest, XOR pre-swizzled source)
#pragma unroll
  for (int i = 0; i < 8; ++i) {
    int id = tid + i * 256;
    int row = id >> 5, kc = id & 31;
    GLOAD_LDS16(WB + (size_t)row * HID + ((kc ^ (row & 15)) << 3), Ps + id * 8);
  }

  // A-frags -> registers ONCE
  int ar = row0 + w * 16 + fr;
  ar = ar < NN ? ar : NN - 1;
  bf16x8 af[8];
#pragma unroll
  for (int t = 0; t < 8; ++t)
    af[t] = *(const bf16x8*)(A + (size_t)ar * HID + t * 32 + fg * 8);

  __syncthreads();   // panel 0 + A-frags landed

#pragma unroll
  for (int p = 0; p < NP; ++p) {
    f32x4 acc[4];
    acc[0] = acc[1] = acc[2] = acc[3] = (f32x4)(0.0f);
#pragma unroll
    for (int t = 0; t < 8; ++t) {
#pragma unroll
      for (int nf = 0; nf < 4; ++nf) {
        int rr = nf * 16 + fr;
        bf16x8 bh = *(const bf16x8*)(Ps + rr * 256 + (((t * 4 + fg) ^ (rr & 15)) << 3));
        acc[nf] = __builtin_amdgcn_mfma_f32_16x16x32_bf16(af[t], bh, acc[nf], 0, 0, 0);
      }
    }

    if constexpr (!GRUE) {
#pragma unroll
      for (int nf = 0; nf < 4; ++nf) {
        int c = p * 64 + nf * 16 + fr;
        float bs = bias[c];
#pragma unroll
        for (int j = 0; j < 4; ++j) {
          int row = row0 + w * 16 + fg * 4 + j;
          if (row < NN) {
            float v = fmaxf(acc[nf][j] + bs, 0.0f);
            size_t off = (size_t)row * HID + c;
            if constexpr (BF16O) outH[off] = (short)f2bf(v);
            if constexpr (F8O) {
              unsigned int r8 = __builtin_amdgcn_cvt_pk_fp8_f32(v, v, 0u, false);
              outF8[off] = (unsigned char)(r8 & 0xFF);
            }
          }
        }
      }
    } else {
      const int u = p * 16 + fr;
      const float cr = cst[u], cz = cst[256 + u], ci = cst[512 + u], chn = cst[768 + u];
#pragma unroll
      for (int j = 0; j < 4; ++j) {
        int row = row0 + w * 16 + fg * 4 + j;
        if (row < NN) {
          float dr = acc[0][j] + cr;
          float dz = acc[1][j] + cz;
          float dn = acc[2][j] + ci;
          float dh = acc[3][j] + chn;
          float rg = fast_sig(dr);
          float zg = fast_sig(dz);
          float ng = fast_tanh(dn + rg * dh);
          size_t off = (size_t)row * HID + u;
          float hv = bf2f((unsigned short)A[off]);
          outF[off] = (1.0f - zg) * ng + zg * hv;
        }
      }
    }

    if (p + 1 < NP) {
      __syncthreads();   // all waves done reading Ps
#pragma unroll
      for (int i = 0; i < 8; ++i) {
        int id = tid + i * 256;
        int row = id >> 5, kc = id & 31;
        GLOAD_LDS16(WB + (size_t)((p + 1) * 64 + row) * HID + ((kc ^ (row & 15)) << 3),
                    Ps + id * 8);
      }
      __syncthreads();   // next panel landed (implicit vmcnt drain)
    }
  }
}

extern "C" void kernel_launch(void* const* d_in, const int* in_sizes, int n_in,
                              void* d_out, int out_size, void* d_ws, size_t ws_size,
                              hipStream_t stream) {
  const float* hidden = (const float*)d_in[0];
  const float* t      = (const float*)d_in[1];
  const int*   src    = (const int*)d_in[2];
  const int*   dst    = (const int*)d_in[3];
  const float* W1     = (const float*)d_in[4];
  const float* b1     = (const float*)d_in[5];
  const float* W2     = (const float*)d_in[6];
  const float* b2     = (const float*)d_in[7];
  const float* time_w = (const float*)d_in[8];
  const float* time_b = (const float*)d_in[9];
  const float* W_ih   = (const float*)d_in[10];
  const float* W_hh   = (const float*)d_in[11];
  const float* b_ih   = (const float*)d_in[12];
  const float* b_hh   = (const float*)d_in[13];
  float* out = (float*)d_out;

  char* p = (char*)d_ws;
  float* onorm = (float*)p;      p += 50048 * 4;
  float* inorm = (float*)p;      p += 50048 * 4;
  float* cst   = (float*)p;      p += 1024 * 4;
  int* rowstart = (int*)p;       p += 50052 * 4;
  int* icnt     = (int*)p;       p += 50048 * 4;
  uint2* epk    = (uint2*)p;     p += 800000 * 8;
  const size_t NFE = (size_t)NN * HID;
  short* Xb   = (short*)p;       p += NFE * 2;
  short* aggB = (short*)p;       p += NFE * 2;
  short* h1B  = (short*)p;       p += NFE * 2;   // P scratch only (dead plane)
  short* h2B  = (short*)p;       p += NFE * 2;
  unsigned char* Xf8  = (unsigned char*)p;  p += NFE;
  unsigned char* h1F8 = (unsigned char*)p;  p += NFE;
  short* W1B  = (short*)p;       p += 65536 * 2;
  short* W2B  = (short*)p;       p += 65536 * 2;
  short* WgB  = (short*)p;       p += 262144 * 2;
  // P = 8*NSL*CHB ints = 33.5 MB over h1B+h2B (51.2 MB contiguous); consumed by
  // fill_csr2 before the layer-2 GEMM writes h2B (stream-ordered).
  int* P = (int*)h1B;

  // prep A: histograms + hidden->bf16/fp8 in one launch; weight prep
  const int cvt_blocks = (NN * HID / 4 + 1023) / 1024;
  prep_a<<<8 * NSL + cvt_blocks, 1024, 0, stream>>>(src, dst, P, hidden, Xb, Xf8);
  wprep<<<513, 256, 0, stream>>>(W1, W2, W_ih, W_hh, t, time_w, time_b, b_ih, b_hh,
                                 W1B, W2B, WgB, cst);

  // graph prep: norms/prefix -> row scan -> LDS-cursor fill (packed records)
  hist_reduce<<<(4 * CHB + 255) / 256, 256, 0, stream>>>(P, onorm, inorm, icnt);
  scan_rows<<<1, 1024, 0, stream>>>(icnt, rowstart);
  fill_csr2<<<4 * NSL, 1024, 0, stream>>>(src, dst, onorm, rowstart, P, epk);

  const int gather_blocks = (NN + 3) / 4;
  const int gblocks = (NN + 63) / 64;   // 782

  // layer 1: fp8 gather + A-resident panel GEMM -> fp8 h1 plane only
  gather_agg<<<gather_blocks, 256, 0, stream>>>(Xf8, rowstart, epk, inorm, aggB);
  panel_gemm<4, false, false, true><<<gblocks, 256, 0, stream>>>(aggB, W1B, b1, nullptr, nullptr, h1F8, nullptr);

  // layer 2: fp8 gather + panel GEMM -> bf16 h2
  gather_agg<<<gather_blocks, 256, 0, stream>>>(h1F8, rowstart, epk, inorm, aggB);
  panel_gemm<4, false, true, false><<<gblocks, 256, 0, stream>>>(aggB, W2B, b2, nullptr, h2B, nullptr, nullptr);

  // GRU: 16 gate panels over 1024 Wg cols, fused gate epilogue -> out
  panel_gemm<16, true, false, false><<<gblocks, 256, 0, stream>>>(h2B, WgB, nullptr, cst, nullptr, nullptr, out);
}